// Round 4
// baseline (5140.037 us; speedup 1.0000x reference)
//
#include <hip/hip_runtime.h>

// Problem constants: B=32, D=128, T=2250, Q=32, K=1024
#define B_ 32
#define D_ 128
#define T_ 2250
#define Q_ 32
#define K_ 1024
#define N_ (B_ * T_)      // 72000 = 64 * 1125
#define TAU 0.25f
#define COFF 640.0f       // score offset: v = 2 r.e + (COFF - ||e||^2), positive for this data

typedef _Float16 half8 __attribute__((ext_vector_type(8)));
typedef float f32x4 __attribute__((ext_vector_type(4)));

__device__ __forceinline__ unsigned int pack2h(float a, float b) {
    _Float16 ha = (_Float16)a, hb = (_Float16)b;
    unsigned short ua = *(unsigned short*)&ha, ub = *(unsigned short*)&hb;
    return (unsigned int)ua | ((unsigned int)ub << 16);
}

__device__ __forceinline__ unsigned int umax_(unsigned int a, unsigned int b) { return a > b ? a : b; }
__device__ __forceinline__ unsigned int umin_(unsigned int a, unsigned int b) { return a < b ? a : b; }

// ---------------------------------------------------------------------------
// Transpose embeddings [B, D, T] -> X32 [N,128] fp32 (n = b*T + t)
// ---------------------------------------------------------------------------
__global__ void transpose_kernel(const float* __restrict__ emb,
                                 float* __restrict__ X32)
{
    __shared__ float tile[32][33];
    const int b  = blockIdx.z;
    const int t0 = blockIdx.x * 32;
    const int d0 = blockIdx.y * 32;

    for (int i = threadIdx.y; i < 32; i += 8) {
        int t = t0 + threadIdx.x;
        int d = d0 + i;
        tile[i][threadIdx.x] = (t < T_) ? emb[((size_t)b * D_ + d) * T_ + t] : 0.0f;
    }
    __syncthreads();
    for (int i = threadIdx.y; i < 32; i += 8) {
        int t = t0 + i;
        if (t < T_) {
            size_t o = ((size_t)b * T_ + t) * D_ + d0 + threadIdx.x;
            X32[o] = tile[threadIdx.x][i];
        }
    }
}

// ---------------------------------------------------------------------------
// Codebook conversion: E16 = fp16(2*e)   [Q*K*D]
// ---------------------------------------------------------------------------
__global__ void cvt_cb_kernel(const float* __restrict__ cbs,
                              _Float16* __restrict__ E16)
{
    int i = blockIdx.x * 256 + threadIdx.x;   // Q*K*D threads exactly
    E16[i] = (_Float16)(2.0f * cbs[i]);
}

// ---------------------------------------------------------------------------
// Per-code norms: cNorm = COFF - ||e||^2 (fp32), normD = ||e||^2 (fp64)
// ---------------------------------------------------------------------------
__global__ __launch_bounds__(64) void norms_kernel(const float* __restrict__ codebooks,
                                                   float* __restrict__ cNorm,
                                                   double* __restrict__ normD)
{
    const int code = blockIdx.x;            // 0 .. Q*K-1
    const float* e = codebooks + (size_t)code * D_;
    const int lane = threadIdx.x;
    float f0 = e[lane];
    float f1 = e[lane + 64];
    double acc = (double)f0 * (double)f0 + (double)f1 * (double)f1;
    #pragma unroll
    for (int off = 32; off > 0; off >>= 1) acc += __shfl_down(acc, off);
    if (lane == 0) {
        normD[code] = acc;
        cNorm[code] = COFF - (float)acc;
    }
}

// ---------------------------------------------------------------------------
// FUSED persistent RVQ kernel. One block = 64 points, loops over all 32
// layers internally. The authoritative fp64 residual lives in LDS (64 KB,
// granule-XOR-swizzled: 16B granule g of row r stored at g^(r&7) -> all
// fragment/update/init accesses are bank-even). Per layer:
//   1. convert residual -> fp16 MFMA A-fragments in registers (proven
//      value chain: fp64 -> float -> fp16, identical ops)
//   2. proven fp16 MFMA scoring + packed top-2 + butterfly + cross-wave
//      merge (byte-identical decision machinery, TAU=0.25)
//   3. flagged near-ties: inline block-cooperative fp64 rescore, ops and
//      order identical to the proven layer_rescore (bit-exact decisions)
//   4. write indices; subtract chosen code from fp64 residual in LDS
// Residual never touches HBM; the 64-dispatch serial chain becomes one
// launch.
// ---------------------------------------------------------------------------
#define RPTS 8
__global__ __launch_bounds__(256, 2) void fused_rvq(
    const float* __restrict__ X32,            // [N,128] transposed points
    const float* __restrict__ cbAll,          // [Q,K,128] fp32 codebooks
    const _Float16* __restrict__ E16All,      // [Q,K,128] fp16(2e)
    const float* __restrict__ cNormAll,       // [Q,K] COFF - ||e||^2
    const double* __restrict__ normDAll,      // [Q,K] ||e||^2 fp64
    int* __restrict__ outIdx)                 // [Q,N]
{
    __shared__ __align__(16) char ldsR[65536];        // fp64 residual, swizzled
    __shared__ unsigned int m1s[256], m2s[256];       // cross-wave merge [4][64]
    __shared__ int kChoice[64];
    __shared__ int flagRows[64];
    __shared__ int flagCnt;
    __shared__ double redS[4][RPTS];
    __shared__ int    redK[4][RPTS];

    const int tid  = threadIdx.x;
    const int lane = tid & 63;
    const int w    = tid >> 6;
    const int mBase = blockIdx.x * 64;        // grid 1125 -> exact
    const int l15  = lane & 15;
    const int quad = lane >> 4;

    // ---- init: residual = (double)X32 (same values as proven transpose) ----
    {
        const float2* Xv = (const float2*)X32;
        #pragma unroll
        for (int k = 0; k < 16; ++k) {
            const int row = k * 4 + w;
            float2 v = Xv[(size_t)(mBase + row) * 64 + lane];
            double2 dv; dv.x = (double)v.x; dv.y = (double)v.y;
            *(double2*)(ldsR + row * 1024 + ((lane ^ (row & 7)) << 4)) = dv;
        }
    }
    __syncthreads();

    #pragma unroll 1
    for (int q = 0; q < Q_; ++q) {
        const _Float16* E16 = E16All + (size_t)q * K_ * D_;
        const float* cb     = cbAll   + (size_t)q * K_ * D_;
        const float* cNorm  = cNormAll + (size_t)q * K_;
        const double* normD = normDAll + (size_t)q * K_;

        // B lane base: code row = st*128 + w*32 + j*16 + l15 (256 B rows)
        const size_t bLane = ((size_t)(w * 32 + l15)) * 256 + (size_t)quad * 16;
        const char* BB = (const char*)E16 + bLane;

        // issue B(stripe 0) early; A-conversion below covers its latency
        half8 Br[2][4];
        #pragma unroll
        for (int j = 0; j < 2; ++j)
            #pragma unroll
            for (int c = 0; c < 4; ++c)
                Br[j][c] = *(const half8*)(BB + (size_t)c * 64 + (size_t)j * 4096);

        // preload cNorm fragments
        float cnr[8][2];
        #pragma unroll
        for (int s8 = 0; s8 < 8; ++s8)
            #pragma unroll
            for (int j = 0; j < 2; ++j)
                cnr[s8][j] = cNorm[s8 * 128 + w * 32 + j * 16 + l15];

        // ---- A fragments: fp64 LDS -> fp16 regs (proven value chain) ----
        half8 A[4][4];                        // [i][c]
        const int srow = l15 & 7;
        #pragma unroll
        for (int i = 0; i < 4; ++i) {
            const char* rp = ldsR + (l15 + 16 * i) * 1024;
            #pragma unroll
            for (int c = 0; c < 4; ++c) {
                const int gb = c * 16 + quad * 4;
                double2 d0 = *(const double2*)(rp + (((gb + 0) ^ srow) << 4));
                double2 d1 = *(const double2*)(rp + (((gb + 1) ^ srow) << 4));
                double2 d2 = *(const double2*)(rp + (((gb + 2) ^ srow) << 4));
                double2 d3 = *(const double2*)(rp + (((gb + 3) ^ srow) << 4));
                half8 hv;
                hv[0] = (_Float16)(float)d0.x; hv[1] = (_Float16)(float)d0.y;
                hv[2] = (_Float16)(float)d1.x; hv[3] = (_Float16)(float)d1.y;
                hv[4] = (_Float16)(float)d2.x; hv[5] = (_Float16)(float)d2.y;
                hv[6] = (_Float16)(float)d3.x; hv[7] = (_Float16)(float)d3.y;
                A[i][c] = hv;
            }
        }

        // packed running top-2 for this lane's 16 points (s = i*4 + r)
        unsigned int b1[16], b2[16];
        #pragma unroll
        for (int s = 0; s < 16; ++s) { b1[s] = 0u; b2[s] = 0u; }

        #pragma unroll 1
        for (int st = 0; st < 8; ++st) {
            f32x4 acc[4][2];
            #pragma unroll
            for (int i = 0; i < 4; ++i)
                #pragma unroll
                for (int j = 0; j < 2; ++j) acc[i][j] = (f32x4){0.f, 0.f, 0.f, 0.f};

            #pragma unroll
            for (int c = 0; c < 4; ++c)
                #pragma unroll
                for (int i = 0; i < 4; ++i)
                    #pragma unroll
                    for (int j = 0; j < 2; ++j)
                        acc[i][j] = __builtin_amdgcn_mfma_f32_16x16x32_f16(A[i][c], Br[j][c], acc[i][j], 0, 0, 0);

            // reload B for next stripe; epilogue covers latency
            {
                const size_t soff = (size_t)((st < 7) ? st + 1 : 7) * 32768;
                #pragma unroll
                for (int j = 0; j < 2; ++j)
                    #pragma unroll
                    for (int c = 0; c < 4; ++c)
                        Br[j][c] = *(const half8*)(BB + soff + (size_t)c * 64 + (size_t)j * 4096);
            }

            // epilogue: pack scores, update packed top-2 (proven semantics)
            #pragma unroll
            for (int j = 0; j < 2; ++j) {
                const int code = st * 128 + w * 32 + j * 16 + l15;
                const float cn = cnr[st][j];
                const unsigned int invc = 1023u - (unsigned int)code;
                #pragma unroll
                for (int i = 0; i < 4; ++i)
                    #pragma unroll
                    for (int r = 0; r < 4; ++r) {
                        float v = fmaxf(acc[i][j][r] + cn, 1.0f);    // positive -> uint-ordered
                        unsigned int p = (__float_as_uint(v) & 0xFFFFFC00u) | invc;
                        const int s = i * 4 + r;
                        unsigned int t  = umax_(b1[s], p);
                        unsigned int mn = umin_(b1[s], p);
                        b2[s] = umax_(b2[s], mn);
                        b1[s] = t;
                    }
            }
        }

        // ---- cross-l15 merge (butterfly over low 4 lane bits) ----
        #pragma unroll
        for (int m = 1; m < 16; m <<= 1) {
            #pragma unroll
            for (int s = 0; s < 16; ++s) {
                unsigned int o1 = (unsigned int)__shfl_xor((int)b1[s], m);
                unsigned int o2 = (unsigned int)__shfl_xor((int)b2[s], m);
                unsigned int n1 = umax_(b1[s], o1);
                unsigned int mn = umin_(b1[s], o1);
                unsigned int mx2 = umax_(b2[s], o2);
                b2[s] = umax_(mn, mx2);
                b1[s] = n1;
            }
        }

        __syncthreads();                       // m1s/m2s free (prev layer done)
        if (l15 == 0) {
            #pragma unroll
            for (int i = 0; i < 4; ++i)
                #pragma unroll
                for (int r = 0; r < 4; ++r) {
                    int p = i * 16 + quad * 4 + r;
                    m1s[w * 64 + p] = b1[i * 4 + r];
                    m2s[w * 64 + p] = b2[i * 4 + r];
                }
        }
        if (tid == 0) flagCnt = 0;
        __syncthreads();

        if (tid < 64) {
            unsigned int f1 = m1s[tid], f2 = m2s[tid];
            #pragma unroll
            for (int ww = 1; ww < 4; ++ww) {
                unsigned int c1 = m1s[ww * 64 + tid], c2 = m2s[ww * 64 + tid];
                unsigned int mn  = umin_(f1, c1);
                f1               = umax_(f1, c1);
                unsigned int mx2 = umax_(f2, c2);
                f2 = umax_(mn, mx2);
            }
            kChoice[tid] = 1023 - (int)(f1 & 0x3FFu);
            float g1 = __uint_as_float(f1 & 0xFFFFFC00u);
            float g2 = __uint_as_float(f2 & 0xFFFFFC00u);
            if (g1 - g2 < TAU) {
                int pos = atomicAdd(&flagCnt, 1);
                flagRows[pos] = tid;
            }
        }
        __syncthreads();

        // ---- inline fp64 rescore of flagged rows (proven ops, batched 8) ----
        const int fc = flagCnt;
        for (int fbase = 0; fbase < fc; fbase += RPTS) {
            const int npts = ((fc - fbase) < RPTS) ? (fc - fbase) : RPTS;
            int prow[RPTS];
            #pragma unroll
            for (int p = 0; p < RPTS; ++p)
                prow[p] = flagRows[(p < npts) ? (fbase + p) : fbase];

            const float* __restrict__ c0 = cb + (size_t)tid * 4 * D_;
            double acc8[4][RPTS];
            #pragma unroll
            for (int cc = 0; cc < 4; ++cc)
                #pragma unroll
                for (int p = 0; p < RPTS; ++p) acc8[cc][p] = 0.0;

            #pragma unroll 2
            for (int j = 0; j < D_; j += 4) {
                f32x4 cv[4];
                #pragma unroll
                for (int cc = 0; cc < 4; ++cc)
                    cv[cc] = *(const f32x4*)(c0 + cc * D_ + j);
                const int g0 = j >> 1;
                #pragma unroll
                for (int p = 0; p < RPTS; ++p) {
                    const char* rp = ldsR + prow[p] * 1024;
                    const int sr = prow[p] & 7;
                    double2 ra = *(const double2*)(rp + (((g0)     ^ sr) << 4));
                    double2 rb = *(const double2*)(rp + (((g0 + 1) ^ sr) << 4));
                    const double r0 = ra.x, r1 = ra.y, r2 = rb.x, r3 = rb.y;
                    #pragma unroll
                    for (int cc = 0; cc < 4; ++cc) {
                        acc8[cc][p] = fma((double)cv[cc][0], r0, acc8[cc][p]);
                        acc8[cc][p] = fma((double)cv[cc][1], r1, acc8[cc][p]);
                        acc8[cc][p] = fma((double)cv[cc][2], r2, acc8[cc][p]);
                        acc8[cc][p] = fma((double)cv[cc][3], r3, acc8[cc][p]);
                    }
                }
            }

            #pragma unroll
            for (int p = 0; p < RPTS; ++p) {
                double bs = -1.0e300;
                int bk = K_;
                #pragma unroll
                for (int cc = 0; cc < 4; ++cc) {
                    const int k = tid * 4 + cc;
                    double s = 2.0 * acc8[cc][p] - normD[k];
                    if (s > bs) { bs = s; bk = k; }   // ascending cc: lowest k wins
                }
                #pragma unroll
                for (int m = 1; m < 64; m <<= 1) {
                    double os = __shfl_xor(bs, m);
                    int    ok = __shfl_xor(bk, m);
                    if (os > bs || (os == bs && ok < bk)) { bs = os; bk = ok; }
                }
                if (lane == 0) { redS[w][p] = bs; redK[w][p] = bk; }
            }
            __syncthreads();
            if (tid < npts) {
                double bs = redS[0][tid];
                int    bk = redK[0][tid];
                #pragma unroll
                for (int ww = 1; ww < 4; ++ww) {
                    double s = redS[ww][tid];
                    int    k = redK[ww][tid];
                    if (s > bs || (s == bs && k < bk)) { bs = s; bk = k; }
                }
                kChoice[flagRows[fbase + tid]] = bk;
            }
            __syncthreads();
        }

        // ---- write indices; subtract chosen code from fp64 residual ----
        if (tid < 64) outIdx[(size_t)q * N_ + mBase + tid] = kChoice[tid];

        if (q < Q_ - 1) {
            const float2* cbv = (const float2*)cb;
            #pragma unroll
            for (int k = 0; k < 16; ++k) {
                const int row = k * 4 + w;
                const int code = kChoice[row];               // wave-uniform
                float2 ev = cbv[(size_t)code * 64 + lane];   // coalesced row
                char* p = ldsR + row * 1024 + ((lane ^ (row & 7)) << 4);
                double2 rv = *(double2*)p;
                rv.x -= (double)ev.x;
                rv.y -= (double)ev.y;
                *(double2*)p = rv;
            }
        }
        __syncthreads();
    }
}

// ---------------------------------------------------------------------------
extern "C" void kernel_launch(void* const* d_in, const int* in_sizes, int n_in,
                              void* d_out, int out_size, void* d_ws, size_t ws_size,
                              hipStream_t stream)
{
    const float* emb       = (const float*)d_in[0];   // [B, D, T] fp32
    const float* codebooks = (const float*)d_in[1];   // [Q, K, D] fp32
    int* outIdx = (int*)d_out;                        // [Q, B, T] int32

    char* ws = (char*)d_ws;
    float* X32 = (float*)ws;                           size_t off = (size_t)N_ * D_ * 4;
    double* normD = (double*)(ws + off);               off += (size_t)Q_ * K_ * 8;
    _Float16* E16 = (_Float16*)(ws + off);             off += (size_t)Q_ * K_ * D_ * 2;
    float* cNorm = (float*)(ws + off);                 off += (size_t)Q_ * K_ * 4;

    dim3 tb(32, 8, 1);
    dim3 tg((T_ + 31) / 32, D_ / 32, B_);
    transpose_kernel<<<tg, tb, 0, stream>>>(emb, X32);
    cvt_cb_kernel<<<(Q_ * K_ * D_) / 256, 256, 0, stream>>>(codebooks, E16);
    norms_kernel<<<Q_ * K_, 64, 0, stream>>>(codebooks, cNorm, normD);

    fused_rvq<<<N_ / 64, 256, 0, stream>>>(X32, codebooks, E16, cNorm, normD, outIdx);
}

// Round 6
// 3872.818 us; speedup vs baseline: 1.3272x; 1.3272x over previous
//
#include <hip/hip_runtime.h>

// Problem constants: B=32, D=128, T=2250, Q=32, K=1024
#define B_ 32
#define D_ 128
#define T_ 2250
#define Q_ 32
#define K_ 1024
#define N_ (B_ * T_)      // 72000 = 64 * 1125
#define TAU 0.25f         // near-tie flag threshold (proven)
#define TAU_FB 0.5f       // top-4 insufficiency threshold (worst-case miss needs <=0.17)
#define COFF 640.0f       // score offset: v = 2 r.e + (COFF - ||e||^2), positive for this data

typedef _Float16 half8 __attribute__((ext_vector_type(8)));
typedef float f32x4 __attribute__((ext_vector_type(4)));

__device__ __forceinline__ unsigned int umax_(unsigned int a, unsigned int b) { return a > b ? a : b; }
__device__ __forceinline__ unsigned int umin_(unsigned int a, unsigned int b) { return a < b ? a : b; }

// ---------------------------------------------------------------------------
// Transpose embeddings [B, D, T] -> X32 [N,128] fp32 (n = b*T + t)
// ---------------------------------------------------------------------------
__global__ void transpose_kernel(const float* __restrict__ emb,
                                 float* __restrict__ X32)
{
    __shared__ float tile[32][33];
    const int b  = blockIdx.z;
    const int t0 = blockIdx.x * 32;
    const int d0 = blockIdx.y * 32;

    for (int i = threadIdx.y; i < 32; i += 8) {
        int t = t0 + threadIdx.x;
        int d = d0 + i;
        tile[i][threadIdx.x] = (t < T_) ? emb[((size_t)b * D_ + d) * T_ + t] : 0.0f;
    }
    __syncthreads();
    for (int i = threadIdx.y; i < 32; i += 8) {
        int t = t0 + i;
        if (t < T_) {
            size_t o = ((size_t)b * T_ + t) * D_ + d0 + threadIdx.x;
            X32[o] = tile[threadIdx.x][i];
        }
    }
}

// ---------------------------------------------------------------------------
// Codebook conversion: E16 = fp16(2*e)   [Q*K*D]
// ---------------------------------------------------------------------------
__global__ void cvt_cb_kernel(const float* __restrict__ cbs,
                              _Float16* __restrict__ E16)
{
    int i = blockIdx.x * 256 + threadIdx.x;   // Q*K*D threads exactly
    E16[i] = (_Float16)(2.0f * cbs[i]);
}

// ---------------------------------------------------------------------------
// Per-code norms: cNorm = COFF - ||e||^2 (fp32), normD = ||e||^2 (fp64)
// ---------------------------------------------------------------------------
__global__ __launch_bounds__(64) void norms_kernel(const float* __restrict__ codebooks,
                                                   float* __restrict__ cNorm,
                                                   double* __restrict__ normD)
{
    const int code = blockIdx.x;            // 0 .. Q*K-1
    const float* e = codebooks + (size_t)code * D_;
    const int lane = threadIdx.x;
    float f0 = e[lane];
    float f1 = e[lane + 64];
    double acc = (double)f0 * (double)f0 + (double)f1 * (double)f1;
    #pragma unroll
    for (int off = 32; off > 0; off >>= 1) acc += __shfl_down(acc, off);
    if (lane == 0) {
        normD[code] = acc;
        cNorm[code] = COFF - (float)acc;
    }
}

// ---------------------------------------------------------------------------
// FUSED persistent RVQ (R4-proven base + top-4 candidate shortcut).
// One block = 64 points x 32 layers; authoritative fp64 residual in LDS
// (64 KB, granule-XOR swizzle g^(row&7) -- R4 layout, verbatim). Per layer:
//   1. fp64 LDS -> fp16 A fragments (R4 verbatim value chain)
//   2. fp16 MFMA scoring + packed TOP-4 (insertion keeps b1/b2 bit-identical
//      to the proven top-2) + bitonic merges across lanes/waves
//   3. decision: g1-g2>=TAU -> top1 (proven); g1-g4>=TAU_FB -> fp64 rescore
//      of the 4 candidates only (true argmax provably in-set; worst-case
//      miss needs g1-g4 <= 2*err+quant ~= 0.17, 3x margin); else full-K
//      fp64 rescore (R4-verbatim grouped machinery, rare)
//   4. write indices; subtract chosen code from fp64 residual (R4 verbatim)
// No per-flag 512 KB codebook streams -> blocks stay layer-synced and the
// E16/cb working set stays L2/L3-resident.
// ---------------------------------------------------------------------------
#define RPTS 8
__global__ __launch_bounds__(256, 2) void fused_rvq(
    const float* __restrict__ X32,            // [N,128] transposed points
    const float* __restrict__ cbAll,          // [Q,K,128] fp32 codebooks
    const _Float16* __restrict__ E16All,      // [Q,K,128] fp16(2e)
    const float* __restrict__ cNormAll,       // [Q,K] COFF - ||e||^2
    const double* __restrict__ normDAll,      // [Q,K] ||e||^2 fp64
    int* __restrict__ outIdx)                 // [Q,N]
{
    __shared__ __align__(16) char ldsR[65536];        // fp64 residual, swizzled (R4)
    __shared__ uint4 mm4[256];                        // per-wave top-4 [4][64]
    __shared__ int kChoice[64];
    __shared__ int r4Rows[64];                        // rows for 4-cand rescore
    __shared__ int flagK4[64][4];                     // their candidate codes
    __shared__ int fbRows[64];                        // rows for full-K fallback
    __shared__ int r4Cnt, fbCnt;
    __shared__ double redS[4][RPTS];
    __shared__ int    redK[4][RPTS];

    const int tid  = threadIdx.x;
    const int lane = tid & 63;
    const int w    = tid >> 6;
    const int mBase = blockIdx.x * 64;        // grid 1125 -> exact
    const int l15  = lane & 15;
    const int quad = lane >> 4;

    // ---- init: residual = (double)X32 (R4 verbatim) ----
    {
        const float2* Xv = (const float2*)X32;
        #pragma unroll
        for (int k = 0; k < 16; ++k) {
            const int row = k * 4 + w;
            float2 v = Xv[(size_t)(mBase + row) * 64 + lane];
            double2 dv; dv.x = (double)v.x; dv.y = (double)v.y;
            *(double2*)(ldsR + row * 1024 + ((lane ^ (row & 7)) << 4)) = dv;
        }
    }
    __syncthreads();

    #pragma unroll 1
    for (int q = 0; q < Q_; ++q) {
        const _Float16* E16 = E16All + (size_t)q * K_ * D_;
        const float* cb     = cbAll    + (size_t)q * K_ * D_;
        const float* cNorm  = cNormAll + (size_t)q * K_;
        const double* normD = normDAll + (size_t)q * K_;

        // B lane base: code row = st*128 + w*32 + j*16 + l15 (256 B rows)
        const size_t bLane = ((size_t)(w * 32 + l15)) * 256 + (size_t)quad * 16;
        const char* BB = (const char*)E16 + bLane;

        // issue B(stripe 0) early; A-conversion below covers its latency
        half8 Br[2][4];
        #pragma unroll
        for (int j = 0; j < 2; ++j)
            #pragma unroll
            for (int c = 0; c < 4; ++c)
                Br[j][c] = *(const half8*)(BB + (size_t)c * 64 + (size_t)j * 4096);

        // preload cNorm fragments
        float cnr[8][2];
        #pragma unroll
        for (int s8 = 0; s8 < 8; ++s8)
            #pragma unroll
            for (int j = 0; j < 2; ++j)
                cnr[s8][j] = cNorm[s8 * 128 + w * 32 + j * 16 + l15];

        // ---- A fragments: fp64 LDS -> fp16 regs (R4 verbatim) ----
        half8 A[4][4];                        // [i][c]
        const int srow = l15 & 7;
        #pragma unroll
        for (int i = 0; i < 4; ++i) {
            const char* rp = ldsR + (l15 + 16 * i) * 1024;
            #pragma unroll
            for (int c = 0; c < 4; ++c) {
                const int gb = c * 16 + quad * 4;
                double2 d0 = *(const double2*)(rp + (((gb + 0) ^ srow) << 4));
                double2 d1 = *(const double2*)(rp + (((gb + 1) ^ srow) << 4));
                double2 d2 = *(const double2*)(rp + (((gb + 2) ^ srow) << 4));
                double2 d3 = *(const double2*)(rp + (((gb + 3) ^ srow) << 4));
                half8 hv;
                hv[0] = (_Float16)(float)d0.x; hv[1] = (_Float16)(float)d0.y;
                hv[2] = (_Float16)(float)d1.x; hv[3] = (_Float16)(float)d1.y;
                hv[4] = (_Float16)(float)d2.x; hv[5] = (_Float16)(float)d2.y;
                hv[6] = (_Float16)(float)d3.x; hv[7] = (_Float16)(float)d3.y;
                A[i][c] = hv;
            }
        }

        // packed running top-4 for this lane's 16 points (s = i*4 + r)
        unsigned int b1[16], b2[16], b3[16], b4[16];
        #pragma unroll
        for (int s = 0; s < 16; ++s) { b1[s] = 0u; b2[s] = 0u; b3[s] = 0u; b4[s] = 0u; }

        #pragma unroll 1
        for (int st = 0; st < 8; ++st) {
            f32x4 acc[4][2];
            #pragma unroll
            for (int i = 0; i < 4; ++i)
                #pragma unroll
                for (int j = 0; j < 2; ++j) acc[i][j] = (f32x4){0.f, 0.f, 0.f, 0.f};

            #pragma unroll
            for (int c = 0; c < 4; ++c)
                #pragma unroll
                for (int i = 0; i < 4; ++i)
                    #pragma unroll
                    for (int j = 0; j < 2; ++j)
                        acc[i][j] = __builtin_amdgcn_mfma_f32_16x16x32_f16(A[i][c], Br[j][c], acc[i][j], 0, 0, 0);

            // reload B for next stripe; epilogue covers its latency
            {
                const size_t soff = (size_t)((st < 7) ? st + 1 : 7) * 32768;
                #pragma unroll
                for (int j = 0; j < 2; ++j)
                    #pragma unroll
                    for (int c = 0; c < 4; ++c)
                        Br[j][c] = *(const half8*)(BB + soff + (size_t)c * 64 + (size_t)j * 4096);
            }

            // epilogue: pack scores (R4 verbatim), sorted top-4 insertion
            #pragma unroll
            for (int j = 0; j < 2; ++j) {
                const int code = st * 128 + w * 32 + j * 16 + l15;
                const float cn = cnr[st][j];
                const unsigned int invc = 1023u - (unsigned int)code;
                #pragma unroll
                for (int i = 0; i < 4; ++i)
                    #pragma unroll
                    for (int r = 0; r < 4; ++r) {
                        float v = fmaxf(acc[i][j][r] + cn, 1.0f);    // positive -> uint-ordered
                        unsigned int p = (__float_as_uint(v) & 0xFFFFFC00u) | invc;
                        const int s = i * 4 + r;
                        unsigned int u1 = umax_(b1[s], p), l1 = umin_(b1[s], p);
                        unsigned int u2 = umax_(b2[s], l1), l2 = umin_(b2[s], l1);
                        unsigned int u3 = umax_(b3[s], l2), l3 = umin_(b3[s], l2);
                        unsigned int u4 = umax_(b4[s], l3);
                        b1[s] = u1; b2[s] = u2; b3[s] = u3; b4[s] = u4;
                    }
            }
        }

        // ---- cross-l15 butterfly merge of sorted top-4 lists ----
        #pragma unroll
        for (int m = 1; m < 16; m <<= 1) {
            #pragma unroll
            for (int s = 0; s < 16; ++s) {
                unsigned int o1 = (unsigned int)__shfl_xor((int)b1[s], m);
                unsigned int o2 = (unsigned int)__shfl_xor((int)b2[s], m);
                unsigned int o3 = (unsigned int)__shfl_xor((int)b3[s], m);
                unsigned int o4 = (unsigned int)__shfl_xor((int)b4[s], m);
                unsigned int m1 = umax_(b1[s], o4), m2 = umax_(b2[s], o3);
                unsigned int m3 = umax_(b3[s], o2), m4 = umax_(b4[s], o1);
                unsigned int x1 = umax_(m1, m3), x3 = umin_(m1, m3);
                unsigned int x2 = umax_(m2, m4), x4 = umin_(m2, m4);
                b1[s] = umax_(x1, x2); b2[s] = umin_(x1, x2);
                b3[s] = umax_(x3, x4); b4[s] = umin_(x3, x4);
            }
        }

        __syncthreads();                       // mm4/kChoice free (prev layer done)
        if (l15 == 0) {
            #pragma unroll
            for (int i = 0; i < 4; ++i)
                #pragma unroll
                for (int r = 0; r < 4; ++r) {
                    const int p = i * 16 + quad * 4 + r;
                    const int s = i * 4 + r;
                    mm4[w * 64 + p] = (uint4){b1[s], b2[s], b3[s], b4[s]};
                }
        }
        if (tid == 0) { r4Cnt = 0; fbCnt = 0; }
        __syncthreads();

        // ---- decision per point: cross-wave merge + classify ----
        if (tid < 64) {
            uint4 a = mm4[tid];
            #pragma unroll
            for (int ww = 1; ww < 4; ++ww) {
                uint4 o = mm4[ww * 64 + tid];
                unsigned int m1 = umax_(a.x, o.w), m2 = umax_(a.y, o.z);
                unsigned int m3 = umax_(a.z, o.y), m4 = umax_(a.w, o.x);
                unsigned int x1 = umax_(m1, m3), x3 = umin_(m1, m3);
                unsigned int x2 = umax_(m2, m4), x4 = umin_(m2, m4);
                a.x = umax_(x1, x2); a.y = umin_(x1, x2);
                a.z = umax_(x3, x4); a.w = umin_(x3, x4);
            }
            const float g1 = __uint_as_float(a.x & 0xFFFFFC00u);
            const float g2 = __uint_as_float(a.y & 0xFFFFFC00u);
            const float g4 = __uint_as_float(a.w & 0xFFFFFC00u);
            kChoice[tid] = 1023 - (int)(a.x & 0x3FFu);
            if (g1 - g2 < TAU) {
                if (g1 - g4 < TAU_FB) {
                    int pos = atomicAdd(&fbCnt, 1);
                    fbRows[pos] = tid;
                } else {
                    int pos = atomicAdd(&r4Cnt, 1);
                    r4Rows[pos] = tid;
                    flagK4[pos][0] = 1023 - (int)(a.x & 0x3FFu);
                    flagK4[pos][1] = 1023 - (int)(a.y & 0x3FFu);
                    flagK4[pos][2] = 1023 - (int)(a.z & 0x3FFu);
                    flagK4[pos][3] = 1023 - (int)(a.w & 0x3FFu);
                }
            }
        }
        __syncthreads();

        const int rc  = r4Cnt;
        const int fbc = fbCnt;

        // ---- 4-candidate fp64 rescore, one wave per flagged point.
        //      Divergence-free: all 64 lanes run every shuffle; quad g owns
        //      candidate g; cross-quad argmax is an all-lane xor tournament.
        for (int f0 = 0; f0 < rc; f0 += 4) {
            const int f = f0 + w;              // wave-uniform
            if (f < rc) {
                const int row = r4Rows[f];
                const int k   = flagK4[f][quad];
                const int sr  = row & 7;
                const char* rp = ldsR + (size_t)row * 1024;
                const float2* ck = (const float2*)(cb + (size_t)k * D_ + l15 * 8);
                double acc = 0.0;
                #pragma unroll
                for (int t = 0; t < 4; ++t) {
                    // fp64 granule l15*4+t holds dims l15*8+2t, +1
                    double2 rv = *(const double2*)(rp + (((l15 * 4 + t) ^ sr) << 4));
                    float2 cv = ck[t];
                    acc = fma((double)cv.x, rv.x, acc);
                    acc = fma((double)cv.y, rv.y, acc);
                }
                #pragma unroll
                for (int m = 1; m < 16; m <<= 1) acc += __shfl_xor(acc, m);
                double bs = 2.0 * acc - normD[k];
                int bk = k;
                #pragma unroll
                for (int m = 16; m < 64; m <<= 1) {
                    double os = __shfl_xor(bs, m);
                    int    ok = __shfl_xor(bk, m);
                    if (os > bs || (os == bs && ok < bk)) { bs = os; bk = ok; }
                }
                if (lane == 0) kChoice[row] = bk;
            }
        }
        __syncthreads();

        // ---- rare full-K fp64 fallback: R4-verbatim grouped rescore ----
        for (int fbase = 0; fbase < fbc; fbase += RPTS) {
            const int rem  = fbc - fbase;
            const int npts = (rem < RPTS) ? rem : RPTS;
            int prow[RPTS];
            #pragma unroll
            for (int p = 0; p < RPTS; ++p)
                prow[p] = fbRows[(p < npts) ? (fbase + p) : fbase];

            const float* __restrict__ c0 = cb + (size_t)tid * 4 * D_;
            double acc8[4][RPTS];
            #pragma unroll
            for (int cc = 0; cc < 4; ++cc)
                #pragma unroll
                for (int p = 0; p < RPTS; ++p) acc8[cc][p] = 0.0;

            #pragma unroll 2
            for (int j = 0; j < D_; j += 4) {
                f32x4 cv[4];
                #pragma unroll
                for (int cc = 0; cc < 4; ++cc)
                    cv[cc] = *(const f32x4*)(c0 + cc * D_ + j);
                const int g0 = j >> 1;
                #pragma unroll
                for (int p = 0; p < RPTS; ++p) {
                    const char* rp = ldsR + (size_t)prow[p] * 1024;
                    const int sr = prow[p] & 7;
                    double2 ra = *(const double2*)(rp + (((g0)     ^ sr) << 4));
                    double2 rb = *(const double2*)(rp + (((g0 + 1) ^ sr) << 4));
                    const double r0 = ra.x, r1 = ra.y, r2 = rb.x, r3 = rb.y;
                    #pragma unroll
                    for (int cc = 0; cc < 4; ++cc) {
                        acc8[cc][p] = fma((double)cv[cc][0], r0, acc8[cc][p]);
                        acc8[cc][p] = fma((double)cv[cc][1], r1, acc8[cc][p]);
                        acc8[cc][p] = fma((double)cv[cc][2], r2, acc8[cc][p]);
                        acc8[cc][p] = fma((double)cv[cc][3], r3, acc8[cc][p]);
                    }
                }
            }

            #pragma unroll
            for (int p = 0; p < RPTS; ++p) {
                double bs = -1.0e300;
                int bk = K_;
                #pragma unroll
                for (int cc = 0; cc < 4; ++cc) {
                    const int k = tid * 4 + cc;
                    double s = 2.0 * acc8[cc][p] - normD[k];
                    if (s > bs) { bs = s; bk = k; }   // ascending cc: lowest k wins
                }
                #pragma unroll
                for (int m = 1; m < 64; m <<= 1) {
                    double os = __shfl_xor(bs, m);
                    int    ok = __shfl_xor(bk, m);
                    if (os > bs || (os == bs && ok < bk)) { bs = os; bk = ok; }
                }
                if (lane == 0) { redS[w][p] = bs; redK[w][p] = bk; }
            }
            __syncthreads();
            if (tid < npts) {
                double bs = redS[0][tid];
                int    bk = redK[0][tid];
                #pragma unroll
                for (int ww = 1; ww < 4; ++ww) {
                    double s = redS[ww][tid];
                    int    k = redK[ww][tid];
                    if (s > bs || (s == bs && k < bk)) { bs = s; bk = k; }
                }
                kChoice[fbRows[fbase + tid]] = bk;
            }
            __syncthreads();
        }
        __syncthreads();

        // ---- write indices; subtract chosen code from fp64 residual (R4) ----
        if (tid < 64) outIdx[(size_t)q * N_ + mBase + tid] = kChoice[tid];

        if (q < Q_ - 1) {
            const float2* cbv = (const float2*)cb;
            #pragma unroll
            for (int k = 0; k < 16; ++k) {
                const int row = k * 4 + w;
                const int code = kChoice[row];               // wave-uniform
                float2 ev = cbv[(size_t)code * 64 + lane];   // coalesced row
                char* p = ldsR + row * 1024 + ((lane ^ (row & 7)) << 4);
                double2 rv = *(double2*)p;
                rv.x -= (double)ev.x;
                rv.y -= (double)ev.y;
                *(double2*)p = rv;
            }
        }
        __syncthreads();
    }
}

// ---------------------------------------------------------------------------
extern "C" void kernel_launch(void* const* d_in, const int* in_sizes, int n_in,
                              void* d_out, int out_size, void* d_ws, size_t ws_size,
                              hipStream_t stream)
{
    const float* emb       = (const float*)d_in[0];   // [B, D, T] fp32
    const float* codebooks = (const float*)d_in[1];   // [Q, K, D] fp32
    int* outIdx = (int*)d_out;                        // [Q, B, T] int32

    char* ws = (char*)d_ws;
    float* X32 = (float*)ws;                           size_t off = (size_t)N_ * D_ * 4;
    double* normD = (double*)(ws + off);               off += (size_t)Q_ * K_ * 8;
    _Float16* E16 = (_Float16*)(ws + off);             off += (size_t)Q_ * K_ * D_ * 2;
    float* cNorm = (float*)(ws + off);                 off += (size_t)Q_ * K_ * 4;

    dim3 tb(32, 8, 1);
    dim3 tg((T_ + 31) / 32, D_ / 32, B_);
    transpose_kernel<<<tg, tb, 0, stream>>>(emb, X32);
    cvt_cb_kernel<<<(Q_ * K_ * D_) / 256, 256, 0, stream>>>(codebooks, E16);
    norms_kernel<<<Q_ * K_, 64, 0, stream>>>(codebooks, cNorm, normD);

    fused_rvq<<<N_ / 64, 256, 0, stream>>>(X32, codebooks, E16, cNorm, normD, outIdx);
}

// Round 9
// 3295.749 us; speedup vs baseline: 1.5596x; 1.1751x over previous
//
#include <hip/hip_runtime.h>

// Problem constants: B=32, D=128, T=2250, Q=32, K=1024
#define B_ 32
#define D_ 128
#define T_ 2250
#define Q_ 32
#define K_ 1024
#define N_ (B_ * T_)      // 72000 = 64 * 1125
#define TAU 0.25f         // near-tie flag threshold (proven)
#define TAU_FB 0.5f       // top-4 insufficiency threshold (worst-case miss needs <=0.17)
#define COFF 640.0f       // score offset: v = 2 r.e + (COFF - ||e||^2), positive for this data

typedef _Float16 half8 __attribute__((ext_vector_type(8)));
typedef float f32x4 __attribute__((ext_vector_type(4)));

__device__ __forceinline__ unsigned int umax_(unsigned int a, unsigned int b) { return a > b ? a : b; }
__device__ __forceinline__ unsigned int umin_(unsigned int a, unsigned int b) { return a < b ? a : b; }
// single-instruction median-of-3: V_MED3_U32 (sorted-insert workhorse)
__device__ __forceinline__ unsigned int med3u(unsigned int a, unsigned int b, unsigned int c) {
    unsigned int d;
    asm("v_med3_u32 %0, %1, %2, %3" : "=v"(d) : "v"(a), "v"(b), "v"(c));
    return d;
}

// ---------------------------------------------------------------------------
// Transpose embeddings [B, D, T] -> X32 [N,128] fp32 (n = b*T + t)
// ---------------------------------------------------------------------------
__global__ void transpose_kernel(const float* __restrict__ emb,
                                 float* __restrict__ X32)
{
    __shared__ float tile[32][33];
    const int b  = blockIdx.z;
    const int t0 = blockIdx.x * 32;
    const int d0 = blockIdx.y * 32;

    for (int i = threadIdx.y; i < 32; i += 8) {
        int t = t0 + threadIdx.x;
        int d = d0 + i;
        tile[i][threadIdx.x] = (t < T_) ? emb[((size_t)b * D_ + d) * T_ + t] : 0.0f;
    }
    __syncthreads();
    for (int i = threadIdx.y; i < 32; i += 8) {
        int t = t0 + i;
        if (t < T_) {
            size_t o = ((size_t)b * T_ + t) * D_ + d0 + threadIdx.x;
            X32[o] = tile[threadIdx.x][i];
        }
    }
}

// ---------------------------------------------------------------------------
// Codebook conversion: E16 = fp16(2*e)   [Q*K*D]
// ---------------------------------------------------------------------------
__global__ void cvt_cb_kernel(const float* __restrict__ cbs,
                              _Float16* __restrict__ E16)
{
    int i = blockIdx.x * 256 + threadIdx.x;   // Q*K*D threads exactly
    E16[i] = (_Float16)(2.0f * cbs[i]);
}

// ---------------------------------------------------------------------------
// Per-code norms: cNorm = COFF - ||e||^2 (fp32), normD = ||e||^2 (fp64)
// ---------------------------------------------------------------------------
__global__ __launch_bounds__(64) void norms_kernel(const float* __restrict__ codebooks,
                                                   float* __restrict__ cNorm,
                                                   double* __restrict__ normD)
{
    const int code = blockIdx.x;            // 0 .. Q*K-1
    const float* e = codebooks + (size_t)code * D_;
    const int lane = threadIdx.x;
    float f0 = e[lane];
    float f1 = e[lane + 64];
    double acc = (double)f0 * (double)f0 + (double)f1 * (double)f1;
    #pragma unroll
    for (int off = 32; off > 0; off >>= 1) acc += __shfl_down(acc, off);
    if (lane == 0) {
        normD[code] = acc;
        cNorm[code] = COFF - (float)acc;
    }
}

// ---------------------------------------------------------------------------
// FUSED persistent RVQ. R9 = R6-proven kernel (fp64 LDS residual chain --
// the R8 bisect proved decisions MUST come from the fp64 chain) with two
// exonerated VALU cuts in the scoring epilogue:
//   (a) cNorm folded into the MFMA accumulator init (rounding-order only)
//   (b) med3-based sorted top-4 insert (provably identical list)
// Everything else (butterflies, decision, 4-cand rescore, full-K fallback,
// fp64 subtract) is R6 verbatim.
// ---------------------------------------------------------------------------
#define RPTS 8
__global__ __launch_bounds__(256, 2) void fused_rvq(
    const float* __restrict__ X32,            // [N,128] transposed points
    const float* __restrict__ cbAll,          // [Q,K,128] fp32 codebooks
    const _Float16* __restrict__ E16All,      // [Q,K,128] fp16(2e)
    const float* __restrict__ cNormAll,       // [Q,K] COFF - ||e||^2
    const double* __restrict__ normDAll,      // [Q,K] ||e||^2 fp64
    int* __restrict__ outIdx)                 // [Q,N]
{
    __shared__ __align__(16) char ldsR[65536];        // fp64 residual, swizzled (R6)
    __shared__ uint4 mm4[256];                        // per-wave top-4 [4][64]
    __shared__ int kChoice[64];
    __shared__ int r4Rows[64];                        // rows for 4-cand rescore
    __shared__ int flagK4[64][4];                     // their candidate codes
    __shared__ int fbRows[64];                        // rows for full-K fallback
    __shared__ int r4Cnt, fbCnt;
    __shared__ double redS[4][RPTS];
    __shared__ int    redK[4][RPTS];

    const int tid  = threadIdx.x;
    const int lane = tid & 63;
    const int w    = tid >> 6;
    const int mBase = blockIdx.x * 64;        // grid 1125 -> exact
    const int l15  = lane & 15;
    const int quad = lane >> 4;

    // ---- init: residual = (double)X32 (R6 verbatim) ----
    {
        const float2* Xv = (const float2*)X32;
        #pragma unroll
        for (int k = 0; k < 16; ++k) {
            const int row = k * 4 + w;
            float2 v = Xv[(size_t)(mBase + row) * 64 + lane];
            double2 dv; dv.x = (double)v.x; dv.y = (double)v.y;
            *(double2*)(ldsR + row * 1024 + ((lane ^ (row & 7)) << 4)) = dv;
        }
    }
    __syncthreads();

    #pragma unroll 1
    for (int q = 0; q < Q_; ++q) {
        const _Float16* E16 = E16All + (size_t)q * K_ * D_;
        const float* cb     = cbAll    + (size_t)q * K_ * D_;
        const float* cNorm  = cNormAll + (size_t)q * K_;
        const double* normD = normDAll + (size_t)q * K_;

        // B lane base: code row = st*128 + w*32 + j*16 + l15 (256 B rows)
        const size_t bLane = ((size_t)(w * 32 + l15)) * 256 + (size_t)quad * 16;
        const char* BB = (const char*)E16 + bLane;

        // issue B(stripe 0) early; A-conversion below covers its latency
        half8 Br[2][4];
        #pragma unroll
        for (int j = 0; j < 2; ++j)
            #pragma unroll
            for (int c = 0; c < 4; ++c)
                Br[j][c] = *(const half8*)(BB + (size_t)c * 64 + (size_t)j * 4096);

        // preload cNorm fragments
        float cnr[8][2];
        #pragma unroll
        for (int s8 = 0; s8 < 8; ++s8)
            #pragma unroll
            for (int j = 0; j < 2; ++j)
                cnr[s8][j] = cNorm[s8 * 128 + w * 32 + j * 16 + l15];

        // ---- A fragments: fp64 LDS -> fp16 regs (R6 verbatim) ----
        half8 A[4][4];                        // [i][c]
        const int srow = l15 & 7;
        #pragma unroll
        for (int i = 0; i < 4; ++i) {
            const char* rp = ldsR + (l15 + 16 * i) * 1024;
            #pragma unroll
            for (int c = 0; c < 4; ++c) {
                const int gb = c * 16 + quad * 4;
                double2 d0 = *(const double2*)(rp + (((gb + 0) ^ srow) << 4));
                double2 d1 = *(const double2*)(rp + (((gb + 1) ^ srow) << 4));
                double2 d2 = *(const double2*)(rp + (((gb + 2) ^ srow) << 4));
                double2 d3 = *(const double2*)(rp + (((gb + 3) ^ srow) << 4));
                half8 hv;
                hv[0] = (_Float16)(float)d0.x; hv[1] = (_Float16)(float)d0.y;
                hv[2] = (_Float16)(float)d1.x; hv[3] = (_Float16)(float)d1.y;
                hv[4] = (_Float16)(float)d2.x; hv[5] = (_Float16)(float)d2.y;
                hv[6] = (_Float16)(float)d3.x; hv[7] = (_Float16)(float)d3.y;
                A[i][c] = hv;
            }
        }

        // packed running top-4 for this lane's 16 points (s = i*4 + r)
        unsigned int b1[16], b2[16], b3[16], b4[16];
        #pragma unroll
        for (int s = 0; s < 16; ++s) { b1[s] = 0u; b2[s] = 0u; b3[s] = 0u; b4[s] = 0u; }

        #pragma unroll 1
        for (int st = 0; st < 8; ++st) {
            // (a) cNorm folded into accumulator init (rounding-order only;
            //     absorbed by the TAU machinery's ~0.1 error budget)
            f32x4 acc[4][2];
            #pragma unroll
            for (int i = 0; i < 4; ++i)
                #pragma unroll
                for (int j = 0; j < 2; ++j) {
                    const float cn = cnr[st][j];
                    acc[i][j] = (f32x4){cn, cn, cn, cn};
                }

            #pragma unroll
            for (int c = 0; c < 4; ++c)
                #pragma unroll
                for (int i = 0; i < 4; ++i)
                    #pragma unroll
                    for (int j = 0; j < 2; ++j)
                        acc[i][j] = __builtin_amdgcn_mfma_f32_16x16x32_f16(A[i][c], Br[j][c], acc[i][j], 0, 0, 0);

            // reload B for next stripe; epilogue covers its latency
            {
                const size_t soff = (size_t)((st < 7) ? st + 1 : 7) * 32768;
                #pragma unroll
                for (int j = 0; j < 2; ++j)
                    #pragma unroll
                    for (int c = 0; c < 4; ++c)
                        Br[j][c] = *(const half8*)(BB + soff + (size_t)c * 64 + (size_t)j * 4096);
            }

            // epilogue: clamp -> pack -> (b) med3 sorted top-4 insert
            #pragma unroll
            for (int j = 0; j < 2; ++j) {
                const int code = st * 128 + w * 32 + j * 16 + l15;
                const unsigned int invc = 1023u - (unsigned int)code;
                #pragma unroll
                for (int i = 0; i < 4; ++i)
                    #pragma unroll
                    for (int r = 0; r < 4; ++r) {
                        float v = fmaxf(acc[i][j][r], 1.0f);    // positive -> uint-ordered
                        unsigned int p = (__float_as_uint(v) & 0xFFFFFC00u) | invc;
                        const int s = i * 4 + r;
                        // sorted insert: b1'=max(b1,p); bk'=med3(b(k-1),bk,p)
                        unsigned int nb1 = umax_(b1[s], p);
                        unsigned int nb2 = med3u(b1[s], b2[s], p);
                        unsigned int nb3 = med3u(b2[s], b3[s], p);
                        unsigned int nb4 = med3u(b3[s], b4[s], p);
                        b1[s] = nb1; b2[s] = nb2; b3[s] = nb3; b4[s] = nb4;
                    }
            }
        }

        // ---- cross-l15 butterfly merge of sorted top-4 lists (R6 verbatim) ----
        #pragma unroll
        for (int m = 1; m < 16; m <<= 1) {
            #pragma unroll
            for (int s = 0; s < 16; ++s) {
                unsigned int o1 = (unsigned int)__shfl_xor((int)b1[s], m);
                unsigned int o2 = (unsigned int)__shfl_xor((int)b2[s], m);
                unsigned int o3 = (unsigned int)__shfl_xor((int)b3[s], m);
                unsigned int o4 = (unsigned int)__shfl_xor((int)b4[s], m);
                unsigned int m1 = umax_(b1[s], o4), m2 = umax_(b2[s], o3);
                unsigned int m3 = umax_(b3[s], o2), m4 = umax_(b4[s], o1);
                unsigned int x1 = umax_(m1, m3), x3 = umin_(m1, m3);
                unsigned int x2 = umax_(m2, m4), x4 = umin_(m2, m4);
                b1[s] = umax_(x1, x2); b2[s] = umin_(x1, x2);
                b3[s] = umax_(x3, x4); b4[s] = umin_(x3, x4);
            }
        }

        __syncthreads();                       // mm4/kChoice free (prev layer done)
        if (l15 == 0) {
            #pragma unroll
            for (int i = 0; i < 4; ++i)
                #pragma unroll
                for (int r = 0; r < 4; ++r) {
                    const int p = i * 16 + quad * 4 + r;
                    const int s = i * 4 + r;
                    mm4[w * 64 + p] = (uint4){b1[s], b2[s], b3[s], b4[s]};
                }
        }
        if (tid == 0) { r4Cnt = 0; fbCnt = 0; }
        __syncthreads();

        // ---- decision per point: cross-wave merge + classify (R6 verbatim) ----
        if (tid < 64) {
            uint4 a = mm4[tid];
            #pragma unroll
            for (int ww = 1; ww < 4; ++ww) {
                uint4 o = mm4[ww * 64 + tid];
                unsigned int m1 = umax_(a.x, o.w), m2 = umax_(a.y, o.z);
                unsigned int m3 = umax_(a.z, o.y), m4 = umax_(a.w, o.x);
                unsigned int x1 = umax_(m1, m3), x3 = umin_(m1, m3);
                unsigned int x2 = umax_(m2, m4), x4 = umin_(m2, m4);
                a.x = umax_(x1, x2); a.y = umin_(x1, x2);
                a.z = umax_(x3, x4); a.w = umin_(x3, x4);
            }
            const float g1 = __uint_as_float(a.x & 0xFFFFFC00u);
            const float g2 = __uint_as_float(a.y & 0xFFFFFC00u);
            const float g4 = __uint_as_float(a.w & 0xFFFFFC00u);
            kChoice[tid] = 1023 - (int)(a.x & 0x3FFu);
            if (g1 - g2 < TAU) {
                if (g1 - g4 < TAU_FB) {
                    int pos = atomicAdd(&fbCnt, 1);
                    fbRows[pos] = tid;
                } else {
                    int pos = atomicAdd(&r4Cnt, 1);
                    r4Rows[pos] = tid;
                    flagK4[pos][0] = 1023 - (int)(a.x & 0x3FFu);
                    flagK4[pos][1] = 1023 - (int)(a.y & 0x3FFu);
                    flagK4[pos][2] = 1023 - (int)(a.z & 0x3FFu);
                    flagK4[pos][3] = 1023 - (int)(a.w & 0x3FFu);
                }
            }
        }
        __syncthreads();

        const int rc  = r4Cnt;
        const int fbc = fbCnt;

        // ---- 4-candidate fp64 rescore (R6 verbatim, divergence-free) ----
        for (int f0 = 0; f0 < rc; f0 += 4) {
            const int f = f0 + w;              // wave-uniform
            if (f < rc) {
                const int row = r4Rows[f];
                const int k   = flagK4[f][quad];
                const int sr  = row & 7;
                const char* rp = ldsR + (size_t)row * 1024;
                const float2* ck = (const float2*)(cb + (size_t)k * D_ + l15 * 8);
                double acc = 0.0;
                #pragma unroll
                for (int t = 0; t < 4; ++t) {
                    // fp64 granule l15*4+t holds dims l15*8+2t, +1
                    double2 rv = *(const double2*)(rp + (((l15 * 4 + t) ^ sr) << 4));
                    float2 cv = ck[t];
                    acc = fma((double)cv.x, rv.x, acc);
                    acc = fma((double)cv.y, rv.y, acc);
                }
                #pragma unroll
                for (int m = 1; m < 16; m <<= 1) acc += __shfl_xor(acc, m);
                double bs = 2.0 * acc - normD[k];
                int bk = k;
                #pragma unroll
                for (int m = 16; m < 64; m <<= 1) {
                    double os = __shfl_xor(bs, m);
                    int    ok = __shfl_xor(bk, m);
                    if (os > bs || (os == bs && ok < bk)) { bs = os; bk = ok; }
                }
                if (lane == 0) kChoice[row] = bk;
            }
        }
        __syncthreads();

        // ---- rare full-K fp64 fallback: R6-verbatim grouped rescore ----
        for (int fbase = 0; fbase < fbc; fbase += RPTS) {
            const int rem  = fbc - fbase;
            const int npts = (rem < RPTS) ? rem : RPTS;
            int prow[RPTS];
            #pragma unroll
            for (int p = 0; p < RPTS; ++p)
                prow[p] = fbRows[(p < npts) ? (fbase + p) : fbase];

            const float* __restrict__ c0 = cb + (size_t)tid * 4 * D_;
            double acc8[4][RPTS];
            #pragma unroll
            for (int cc = 0; cc < 4; ++cc)
                #pragma unroll
                for (int p = 0; p < RPTS; ++p) acc8[cc][p] = 0.0;

            #pragma unroll 2
            for (int j = 0; j < D_; j += 4) {
                f32x4 cv[4];
                #pragma unroll
                for (int cc = 0; cc < 4; ++cc)
                    cv[cc] = *(const f32x4*)(c0 + cc * D_ + j);
                const int g0 = j >> 1;
                #pragma unroll
                for (int p = 0; p < RPTS; ++p) {
                    const char* rp = ldsR + (size_t)prow[p] * 1024;
                    const int sr = prow[p] & 7;
                    double2 ra = *(const double2*)(rp + (((g0)     ^ sr) << 4));
                    double2 rb = *(const double2*)(rp + (((g0 + 1) ^ sr) << 4));
                    const double r0 = ra.x, r1 = ra.y, r2 = rb.x, r3 = rb.y;
                    #pragma unroll
                    for (int cc = 0; cc < 4; ++cc) {
                        acc8[cc][p] = fma((double)cv[cc][0], r0, acc8[cc][p]);
                        acc8[cc][p] = fma((double)cv[cc][1], r1, acc8[cc][p]);
                        acc8[cc][p] = fma((double)cv[cc][2], r2, acc8[cc][p]);
                        acc8[cc][p] = fma((double)cv[cc][3], r3, acc8[cc][p]);
                    }
                }
            }

            #pragma unroll
            for (int p = 0; p < RPTS; ++p) {
                double bs = -1.0e300;
                int bk = K_;
                #pragma unroll
                for (int cc = 0; cc < 4; ++cc) {
                    const int k = tid * 4 + cc;
                    double s = 2.0 * acc8[cc][p] - normD[k];
                    if (s > bs) { bs = s; bk = k; }   // ascending cc: lowest k wins
                }
                #pragma unroll
                for (int m = 1; m < 64; m <<= 1) {
                    double os = __shfl_xor(bs, m);
                    int    ok = __shfl_xor(bk, m);
                    if (os > bs || (os == bs && ok < bk)) { bs = os; bk = ok; }
                }
                if (lane == 0) { redS[w][p] = bs; redK[w][p] = bk; }
            }
            __syncthreads();
            if (tid < npts) {
                double bs = redS[0][tid];
                int    bk = redK[0][tid];
                #pragma unroll
                for (int ww = 1; ww < 4; ++ww) {
                    double s = redS[ww][tid];
                    int    k = redK[ww][tid];
                    if (s > bs || (s == bs && k < bk)) { bs = s; bk = k; }
                }
                kChoice[fbRows[fbase + tid]] = bk;
            }
            __syncthreads();
        }
        __syncthreads();

        // ---- write indices; subtract chosen code from fp64 residual (R6) ----
        if (tid < 64) outIdx[(size_t)q * N_ + mBase + tid] = kChoice[tid];

        if (q < Q_ - 1) {
            const float2* cbv = (const float2*)cb;
            #pragma unroll
            for (int k = 0; k < 16; ++k) {
                const int row = k * 4 + w;
                const int code = kChoice[row];               // wave-uniform
                float2 ev = cbv[(size_t)code * 64 + lane];   // coalesced row
                char* p = ldsR + row * 1024 + ((lane ^ (row & 7)) << 4);
                double2 rv = *(double2*)p;
                rv.x -= (double)ev.x;
                rv.y -= (double)ev.y;
                *(double2*)p = rv;
            }
        }
        __syncthreads();
    }
}

// ---------------------------------------------------------------------------
extern "C" void kernel_launch(void* const* d_in, const int* in_sizes, int n_in,
                              void* d_out, int out_size, void* d_ws, size_t ws_size,
                              hipStream_t stream)
{
    const float* emb       = (const float*)d_in[0];   // [B, D, T] fp32
    const float* codebooks = (const float*)d_in[1];   // [Q, K, D] fp32
    int* outIdx = (int*)d_out;                        // [Q, B, T] int32

    char* ws = (char*)d_ws;
    float* X32 = (float*)ws;                           size_t off = (size_t)N_ * D_ * 4;
    double* normD = (double*)(ws + off);               off += (size_t)Q_ * K_ * 8;
    _Float16* E16 = (_Float16*)(ws + off);             off += (size_t)Q_ * K_ * D_ * 2;
    float* cNorm = (float*)(ws + off);                 off += (size_t)Q_ * K_ * 4;

    dim3 tb(32, 8, 1);
    dim3 tg((T_ + 31) / 32, D_ / 32, B_);
    transpose_kernel<<<tg, tb, 0, stream>>>(emb, X32);
    cvt_cb_kernel<<<(Q_ * K_ * D_) / 256, 256, 0, stream>>>(codebooks, E16);
    norms_kernel<<<Q_ * K_, 64, 0, stream>>>(codebooks, cNorm, normD);

    fused_rvq<<<N_ / 64, 256, 0, stream>>>(X32, codebooks, E16, cNorm, normD, outIdx);
}